// Round 1
// baseline (197.728 us; speedup 1.0000x reference)
//
#include <hip/hip_runtime.h>
#include <cstddef>

// YOLO decode: out[b, ((h*W+w)*3+a), attr] = f(x[b, a*85+attr, h, w])
//   attr 0: (sigmoid(v) + w) * stride
//   attr 1: (sigmoid(v) + h) * stride
//   attr 2: exp(v) * anchor_w_px
//   attr 3: exp(v) * anchor_h_px
//   attr 4: sigmoid(v)
//   attr>=5: sigmoid(idf[attr-5] * v)

#define NATTR 85
#define NCH 255  // 3 anchors * 85 attrs

static __device__ __forceinline__ float sigmoidf_(float x) {
  return 1.0f / (1.0f + __expf(-x));
}

template <int SCALE, int P>
__global__ __launch_bounds__(256) void yolo_decode(
    const float* __restrict__ x, const float* __restrict__ idf,
    float* __restrict__ out) {
  constexpr int W = (SCALE == 0) ? 76 : (SCALE == 1) ? 38 : 19;
  constexpr int HW = W * W;
  constexpr float STRIDE = 608.0f / (float)W;
  constexpr int ROWBASE =
      (SCALE == 0) ? 0 : (SCALE == 1) ? 76 * 76 * 3 : (76 * 76 * 3 + 38 * 38 * 3);
  constexpr int TOTROWS = (76 * 76 + 38 * 38 + 19 * 19) * 3;  // 22743

  __shared__ float lds[P * NCH];
  __shared__ float sidf[80];

  const int b = blockIdx.y;
  const int p0 = blockIdx.x * P;
  const int rem = HW - p0;
  const int np = rem < P ? rem : P;

  if (threadIdx.x < 80) sidf[threadIdx.x] = idf[threadIdx.x];

  const float* src = x + (size_t)b * (NCH * HW) + p0;

  if ((HW % 4 == 0) && np == P) {
    // full tile, HW multiple of 4 -> aligned float4 staging
    constexpr int PV = P / 4;
    for (int i = threadIdx.x; i < NCH * PV; i += 256) {
      const int c = i / PV;
      const int v = i - c * PV;
      const float4 val = *reinterpret_cast<const float4*>(src + (size_t)c * HW + 4 * v);
      const int base = (4 * v) * NCH + c;  // lds[p][c], row stride 255 (odd -> no bank conflict)
      lds[base] = val.x;
      lds[base + NCH] = val.y;
      lds[base + 2 * NCH] = val.z;
      lds[base + 3 * NCH] = val.w;
    }
  } else {
    for (int i = threadIdx.x; i < NCH * np; i += 256) {
      const int c = i / np;
      const int p = i - c * np;
      lds[p * NCH + c] = src[(size_t)c * HW + p];
    }
  }
  __syncthreads();

  // anchor sizes in pixels (exp(v) * a_px directly; the /stride/W * W*stride cancels)
  const float AW0 = (SCALE == 0) ? 10.f : (SCALE == 1) ? 30.f : 116.f;
  const float AW1 = (SCALE == 0) ? 16.f : (SCALE == 1) ? 62.f : 156.f;
  const float AW2 = (SCALE == 0) ? 33.f : (SCALE == 1) ? 59.f : 373.f;
  const float AH0 = (SCALE == 0) ? 13.f : (SCALE == 1) ? 61.f : 90.f;
  const float AH1 = (SCALE == 0) ? 30.f : (SCALE == 1) ? 45.f : 198.f;
  const float AH2 = (SCALE == 0) ? 23.f : (SCALE == 1) ? 119.f : 326.f;

  float* dst = out + ((size_t)b * TOTROWS + ROWBASE + (size_t)p0 * 3) * NATTR;
  const int total = np * NCH;
  for (int i = threadIdx.x; i < total; i += 256) {
    const int p = i / NCH;
    const int j = i - p * NCH;
    const int a = j / NATTR;
    const int attr = j - a * NATTR;
    const float v = lds[i];  // lds[p][a*85+attr] == lds[i] (channel order == output order)

    const int pg = p0 + p;
    const int h = pg / W;
    const int w = pg - h * W;

    float r;
    if (attr >= 5) {
      r = sigmoidf_(sidf[attr - 5] * v);
    } else if (attr == 0) {
      r = (sigmoidf_(v) + (float)w) * STRIDE;
    } else if (attr == 1) {
      r = (sigmoidf_(v) + (float)h) * STRIDE;
    } else if (attr == 2) {
      const float aw = (a == 0) ? AW0 : (a == 1) ? AW1 : AW2;
      r = __expf(v) * aw;
    } else if (attr == 3) {
      const float ah = (a == 0) ? AH0 : (a == 1) ? AH1 : AH2;
      r = __expf(v) * ah;
    } else {  // attr == 4
      r = sigmoidf_(v);
    }
    dst[i] = r;
  }
}

extern "C" void kernel_launch(void* const* d_in, const int* in_sizes, int n_in,
                              void* d_out, int out_size, void* d_ws, size_t ws_size,
                              hipStream_t stream) {
  const float* x0 = (const float*)d_in[0];
  const float* x1 = (const float*)d_in[1];
  const float* x2 = (const float*)d_in[2];
  const float* idf = (const float*)d_in[3];
  float* out = (float*)d_out;

  const int bs = in_sizes[0] / (NCH * 76 * 76);  // 16

  constexpr int P = 64;
  dim3 blk(256);
  yolo_decode<0, P><<<dim3((76 * 76 + P - 1) / P, bs), blk, 0, stream>>>(x0, idf, out);
  yolo_decode<1, P><<<dim3((38 * 38 + P - 1) / P, bs), blk, 0, stream>>>(x1, idf, out);
  yolo_decode<2, P><<<dim3((19 * 19 + P - 1) / P, bs), blk, 0, stream>>>(x2, idf, out);
}

// Round 2
// 64.143 us; speedup vs baseline: 3.0826x; 3.0826x over previous
//
#include <hip/hip_runtime.h>
#include <cstddef>

// YOLO decode: out[b, ((h*W+w)*3+a), attr] = f(x[b, a*85+attr, h, w])
//   attr 0: (sigmoid(v) + w) * stride       (algebra: (sig+cx*W-0.5)*s, cx=(w+.5)/W)
//   attr 1: (sigmoid(v) + h) * stride
//   attr 2: exp(v) * anchor_w_px            (a_px/stride/W * W*stride cancels)
//   attr 3: exp(v) * anchor_h_px
//   attr 4: sigmoid(v)
//   attr>=5: sigmoid(idf[attr-5] * v)

#define NATTR 85
#define NCH 255       // 3 anchors * 85 attrs
#define TILE_P 16     // pixels per block tile
#define TILE_PV 4     // TILE_P / 4

static constexpr int TOTROWS = (76 * 76 + 38 * 38 + 19 * 19) * 3;  // 22743

static __device__ __forceinline__ float sigmoidf_(float x) {
  return 1.0f / (1.0f + __expf(-x));
}

template <int SCALE>
struct Cfg {
  static constexpr int W = (SCALE == 0) ? 76 : (SCALE == 1) ? 38 : 19;
  static constexpr int HW = W * W;
  static constexpr int TILES = (HW + TILE_P - 1) / TILE_P;  // 361 / 91 / 23
  static constexpr float STRIDE = 608.0f / (float)W;
  static constexpr int ROWBASE =
      (SCALE == 0) ? 0 : (SCALE == 1) ? 76 * 76 * 3 : (76 * 76 * 3 + 38 * 38 * 3);
  static constexpr float AW0 = (SCALE == 0) ? 10.f : (SCALE == 1) ? 30.f : 116.f;
  static constexpr float AW1 = (SCALE == 0) ? 16.f : (SCALE == 1) ? 62.f : 156.f;
  static constexpr float AW2 = (SCALE == 0) ? 33.f : (SCALE == 1) ? 59.f : 373.f;
  static constexpr float AH0 = (SCALE == 0) ? 13.f : (SCALE == 1) ? 61.f : 90.f;
  static constexpr float AH1 = (SCALE == 0) ? 30.f : (SCALE == 1) ? 45.f : 198.f;
  static constexpr float AH2 = (SCALE == 0) ? 23.f : (SCALE == 1) ? 119.f : 326.f;
};

template <int SCALE>
static __device__ __forceinline__ float xf(int a, int attr, int p, float v,
                                           const float* __restrict__ sidf) {
  using C = Cfg<SCALE>;
  if (attr >= 5) return sigmoidf_(sidf[attr - 5] * v);   // 80/85 channels take this
  if (attr == 4) return sigmoidf_(v);
  if (attr == 2) {
    const float aw = (a == 0) ? C::AW0 : (a == 1) ? C::AW1 : C::AW2;
    return __expf(v) * aw;
  }
  if (attr == 3) {
    const float ah = (a == 0) ? C::AH0 : (a == 1) ? C::AH1 : C::AH2;
    return __expf(v) * ah;
  }
  const int h = p / C::W;               // constexpr W -> magic mul
  const int w = p - h * C::W;
  return (sigmoidf_(v) + (float)((attr == 0) ? w : h)) * C::STRIDE;
}

// Stage one (batch, 16-pixel) tile through LDS with the transform applied at
// staging (channel known per-load -> div/mod once per 4 elems, near-uniform
// branch); write-out is then a pure contiguous streaming copy.
template <int SCALE>
static __device__ __forceinline__ void decode_tile(
    int b, int t, const float* __restrict__ x, float* __restrict__ out,
    const float* __restrict__ sidf, float* __restrict__ lds) {
  using C = Cfg<SCALE>;
  const int p0 = t * TILE_P;
  const int rem = C::HW - p0;
  const int np = rem < TILE_P ? rem : TILE_P;
  const float* src = x + (size_t)b * (NCH * C::HW) + p0;

  if ((C::HW % 4 == 0) && np == TILE_P) {
    // full tile, aligned float4 staging: thread owns (channel c, float4 v)
    for (int i = threadIdx.x; i < NCH * TILE_PV; i += 256) {
      const int c = i >> 2;
      const int v = i & 3;
      const float4 val = *reinterpret_cast<const float4*>(src + (size_t)c * C::HW + 4 * v);
      const int a = c / NATTR;
      const int attr = c - a * NATTR;
      const int pb = p0 + 4 * v;
      float* dl = lds + (4 * v) * NCH + c;  // lds[p][c], row stride 255
      dl[0]         = xf<SCALE>(a, attr, pb + 0, val.x, sidf);
      dl[NCH]       = xf<SCALE>(a, attr, pb + 1, val.y, sidf);
      dl[2 * NCH]   = xf<SCALE>(a, attr, pb + 2, val.z, sidf);
      dl[3 * NCH]   = xf<SCALE>(a, attr, pb + 3, val.w, sidf);
    }
  } else {
    // tail / odd-HW tile: scalar guarded
    for (int i = threadIdx.x; i < NCH * TILE_P; i += 256) {
      const int c = i >> 4;   // TILE_P = 16
      const int p = i & 15;
      if (p < np) {
        const int a = c / NATTR;
        const int attr = c - a * NATTR;
        const float v = src[(size_t)c * C::HW + p];
        lds[p * NCH + c] = xf<SCALE>(a, attr, p0 + p, v, sidf);
      }
    }
  }
  __syncthreads();

  float* dst = out + ((size_t)b * TOTROWS + C::ROWBASE + (size_t)p0 * 3) * NATTR;
  const int total = np * NCH;
  for (int i = threadIdx.x; i < total; i += 256) dst[i] = lds[i];  // pure stream
}

__global__ __launch_bounds__(256, 5) void yolo_all(
    const float* __restrict__ x0, const float* __restrict__ x1,
    const float* __restrict__ x2, const float* __restrict__ idf,
    float* __restrict__ out, int bs) {
  __shared__ float lds[TILE_P * NCH];
  __shared__ float sidf[80];
  if (threadIdx.x < 80) sidf[threadIdx.x] = idf[threadIdx.x];
  __syncthreads();

  const int nb0 = Cfg<0>::TILES * bs;
  const int nb1 = Cfg<1>::TILES * bs;
  int blk = blockIdx.x;
  if (blk < nb0) {
    decode_tile<0>(blk / Cfg<0>::TILES, blk % Cfg<0>::TILES, x0, out, sidf, lds);
  } else if (blk < nb0 + nb1) {
    blk -= nb0;
    decode_tile<1>(blk / Cfg<1>::TILES, blk % Cfg<1>::TILES, x1, out, sidf, lds);
  } else {
    blk -= nb0 + nb1;
    decode_tile<2>(blk / Cfg<2>::TILES, blk % Cfg<2>::TILES, x2, out, sidf, lds);
  }
}

extern "C" void kernel_launch(void* const* d_in, const int* in_sizes, int n_in,
                              void* d_out, int out_size, void* d_ws, size_t ws_size,
                              hipStream_t stream) {
  const float* x0 = (const float*)d_in[0];
  const float* x1 = (const float*)d_in[1];
  const float* x2 = (const float*)d_in[2];
  const float* idf = (const float*)d_in[3];
  float* out = (float*)d_out;

  const int bs = in_sizes[0] / (NCH * 76 * 76);  // 16
  const int nb = (Cfg<0>::TILES + Cfg<1>::TILES + Cfg<2>::TILES) * bs;  // 475*bs

  yolo_all<<<dim3(nb), dim3(256), 0, stream>>>(x0, x1, x2, idf, out, bs);
}

// Round 3
// 63.374 us; speedup vs baseline: 3.1200x; 1.0121x over previous
//
#include <hip/hip_runtime.h>
#include <cstddef>

// YOLO decode: out[b, ((h*W+w)*3+a), attr] = f(x[b, a*85+attr, h, w])
//   attr 0: (sigmoid(v) + w) * stride
//   attr 1: (sigmoid(v) + h) * stride
//   attr 2: exp(v) * anchor_w_px
//   attr 3: exp(v) * anchor_h_px
//   attr 4: sigmoid(v)
//   attr>=5: sigmoid(idf[attr-5] * v)

#define NATTR 85
#define NCH 255       // 3 anchors * 85 attrs
#define TILE_P 16     // pixels per block tile
#define TILE_PV 4     // TILE_P / 4

static constexpr int TOTROWS = (76 * 76 + 38 * 38 + 19 * 19) * 3;  // 22743

static __device__ __forceinline__ float sigmoidf_(float x) {
  return 1.0f / (1.0f + __expf(-x));
}

template <int SCALE>
struct Cfg {
  static constexpr int W = (SCALE == 0) ? 76 : (SCALE == 1) ? 38 : 19;
  static constexpr int HW = W * W;
  static constexpr int TILES = (HW + TILE_P - 1) / TILE_P;  // 361 / 91 / 23
  static constexpr float STRIDE = 608.0f / (float)W;
  static constexpr int ROWBASE =
      (SCALE == 0) ? 0 : (SCALE == 1) ? 76 * 76 * 3 : (76 * 76 * 3 + 38 * 38 * 3);
  static constexpr float AW0 = (SCALE == 0) ? 10.f : (SCALE == 1) ? 30.f : 116.f;
  static constexpr float AW1 = (SCALE == 0) ? 16.f : (SCALE == 1) ? 62.f : 156.f;
  static constexpr float AW2 = (SCALE == 0) ? 33.f : (SCALE == 1) ? 59.f : 373.f;
  static constexpr float AH0 = (SCALE == 0) ? 13.f : (SCALE == 1) ? 61.f : 90.f;
  static constexpr float AH1 = (SCALE == 0) ? 30.f : (SCALE == 1) ? 45.f : 198.f;
  static constexpr float AH2 = (SCALE == 0) ? 23.f : (SCALE == 1) ? 119.f : 326.f;
};

template <int SCALE>
static __device__ __forceinline__ float xf(int a, int attr, int p, float v,
                                           const float* __restrict__ sidf) {
  using C = Cfg<SCALE>;
  if (attr >= 5) return sigmoidf_(sidf[attr - 5] * v);   // 80/85 channels take this
  if (attr == 4) return sigmoidf_(v);
  if (attr == 2) {
    const float aw = (a == 0) ? C::AW0 : (a == 1) ? C::AW1 : C::AW2;
    return __expf(v) * aw;
  }
  if (attr == 3) {
    const float ah = (a == 0) ? C::AH0 : (a == 1) ? C::AH1 : C::AH2;
    return __expf(v) * ah;
  }
  const int h = p / C::W;               // constexpr W -> magic mul
  const int w = p - h * C::W;
  return (sigmoidf_(v) + (float)((attr == 0) ? w : h)) * C::STRIDE;
}

// Stage one (batch, 16-pixel) tile through LDS with the transform applied at
// staging; write-out is a pure contiguous float4 stream (with scalar head/tail
// since per-batch output base is misaligned by (b&3) floats).
template <int SCALE>
static __device__ __forceinline__ void decode_tile(
    int b, int t, const float* __restrict__ x, float* __restrict__ out,
    const float* __restrict__ sidf, float* __restrict__ lds) {
  using C = Cfg<SCALE>;
  const int p0 = t * TILE_P;
  const int rem = C::HW - p0;
  const int np = rem < TILE_P ? rem : TILE_P;
  const float* src = x + (size_t)b * (NCH * C::HW) + p0;
  const bool full = (C::HW % 4 == 0) && (np == TILE_P);

  if (full) {
    // full tile, aligned float4 staging: thread owns (channel c, float4 v)
    for (int i = threadIdx.x; i < NCH * TILE_PV; i += 256) {
      const int c = i >> 2;
      const int v = i & 3;
      const float4 val = *reinterpret_cast<const float4*>(src + (size_t)c * C::HW + 4 * v);
      const int a = c / NATTR;
      const int attr = c - a * NATTR;
      const int pb = p0 + 4 * v;
      float* dl = lds + (4 * v) * NCH + c;  // lds[p][c], row stride 255
      dl[0]         = xf<SCALE>(a, attr, pb + 0, val.x, sidf);
      dl[NCH]       = xf<SCALE>(a, attr, pb + 1, val.y, sidf);
      dl[2 * NCH]   = xf<SCALE>(a, attr, pb + 2, val.z, sidf);
      dl[3 * NCH]   = xf<SCALE>(a, attr, pb + 3, val.w, sidf);
    }
  } else {
    // tail / odd-HW tile: scalar guarded
    for (int i = threadIdx.x; i < NCH * TILE_P; i += 256) {
      const int c = i >> 4;   // TILE_P = 16
      const int p = i & 15;
      if (p < np) {
        const int a = c / NATTR;
        const int attr = c - a * NATTR;
        const float v = src[(size_t)c * C::HW + p];
        lds[p * NCH + c] = xf<SCALE>(a, attr, p0 + p, v, sidf);
      }
    }
  }
  __syncthreads();

  float* dst = out + ((size_t)b * TOTROWS + C::ROWBASE + (size_t)p0 * 3) * NATTR;
  const int total = np * NCH;

  if (full) {
    // dst float-offset mod 4 == (3b)&3  ->  head = b&3 scalars to reach 16B alignment
    const int head = b & 3;
    if (threadIdx.x < head) dst[threadIdx.x] = lds[threadIdx.x];
    const int nvec = (total - head) >> 2;
    for (int k = threadIdx.x; k < nvec; k += 256) {
      const int o = head + 4 * k;
      float4 val;
      val.x = lds[o];
      val.y = lds[o + 1];
      val.z = lds[o + 2];
      val.w = lds[o + 3];
      *reinterpret_cast<float4*>(dst + o) = val;
    }
    for (int i = head + 4 * nvec + threadIdx.x; i < total; i += 256) dst[i] = lds[i];
  } else {
    for (int i = threadIdx.x; i < total; i += 256) dst[i] = lds[i];
  }
}

__global__ __launch_bounds__(256, 8) void yolo_all(
    const float* __restrict__ x0, const float* __restrict__ x1,
    const float* __restrict__ x2, const float* __restrict__ idf,
    float* __restrict__ out, int bs) {
  __shared__ float lds[TILE_P * NCH];
  __shared__ float sidf[80];
  if (threadIdx.x < 80) sidf[threadIdx.x] = idf[threadIdx.x];
  __syncthreads();

  const int nb0 = Cfg<0>::TILES * bs;
  const int nb1 = Cfg<1>::TILES * bs;
  int blk = blockIdx.x;
  if (blk < nb0) {
    decode_tile<0>(blk / Cfg<0>::TILES, blk % Cfg<0>::TILES, x0, out, sidf, lds);
  } else if (blk < nb0 + nb1) {
    blk -= nb0;
    decode_tile<1>(blk / Cfg<1>::TILES, blk % Cfg<1>::TILES, x1, out, sidf, lds);
  } else {
    blk -= nb0 + nb1;
    decode_tile<2>(blk / Cfg<2>::TILES, blk % Cfg<2>::TILES, x2, out, sidf, lds);
  }
}

extern "C" void kernel_launch(void* const* d_in, const int* in_sizes, int n_in,
                              void* d_out, int out_size, void* d_ws, size_t ws_size,
                              hipStream_t stream) {
  const float* x0 = (const float*)d_in[0];
  const float* x1 = (const float*)d_in[1];
  const float* x2 = (const float*)d_in[2];
  const float* idf = (const float*)d_in[3];
  float* out = (float*)d_out;

  const int bs = in_sizes[0] / (NCH * 76 * 76);  // 16
  const int nb = (Cfg<0>::TILES + Cfg<1>::TILES + Cfg<2>::TILES) * bs;  // 475*bs

  yolo_all<<<dim3(nb), dim3(256), 0, stream>>>(x0, x1, x2, idf, out, bs);
}